// Round 9
// baseline (167.040 us; speedup 1.0000x reference)
//
#include <hip/hip_runtime.h>

// R9: R8's 2-rows-per-wave shape, but the token loop runs entirely on the
// VALU pipe: per-lane token data in registers + v_readlane broadcast
// (no LDS staging, no ds_read in the hot loop). Padded hist layout
// (job@0,rep@11,pad@45,place@46,add@65) makes the embedding weighted sum a
// uniform half-wave-split loop. DS instructions per WG: ~600 -> ~40.
// Algebra unchanged: histogram-weighted table sums, binary-vocab counts as
// index sums, pool<->32x32-matmul commutation.

#define BDIM 64

__device__ __forceinline__ float rlf(float v, int l) {
    return __int_as_float(__builtin_amdgcn_readlane(__float_as_int(v), l));
}

__global__ __launch_bounds__(BDIM)
void mlpreg_kernel(const float* __restrict__ cont_p,
                   const float* __restrict__ cont_c,
                   const int* __restrict__ cat_p,
                   const int* __restrict__ cat_c,
                   const int* __restrict__ lengths,
                   const float* __restrict__ w_p1, const float* __restrict__ b_p1,
                   const float* __restrict__ w_p2, const float* __restrict__ b_p2,
                   const float* __restrict__ w_c1, const float* __restrict__ b_c1,
                   const float* __restrict__ w_c2, const float* __restrict__ b_c2,
                   const float* __restrict__ emb_g,  const float* __restrict__ emb_k,
                   const float* __restrict__ emb_pr, const float* __restrict__ emb_j,
                   const float* __restrict__ emb_r,  const float* __restrict__ emb_pl,
                   const float* __restrict__ emb_a,
                   const float* __restrict__ w_fc1, const float* __restrict__ b_fc1,
                   const float* __restrict__ w_fc2, const float* __restrict__ b_fc2,
                   float* __restrict__ out)
{
    constexpr int S = 256;
    __shared__ int   hist[2][96];     // job@0(11) rep@11(34) pad@45 place@46(19) add@65(31)
    __shared__ float pacc[2][64];
    __shared__ float sPool[2][128];

    const int lane = threadIdx.x;
    const int b0 = blockIdx.x * 2, b1 = b0 + 1;

    int L0 = lengths[b0]; L0 = (L0 < 1) ? 1 : (L0 > S ? S : L0);
    int L1 = lengths[b1]; L1 = (L1 < 1) ? 1 : (L1 > S ? S : L1);
    const float L0f = (float)L0, L1f = (float)L1;
    const float invL0 = 1.0f / L0f, invL1 = 1.0f / L1f;

    // zero hist (192 ints); same-wave DS program order protects later atomics
    ((int*)hist)[lane]       = 0;
    ((int*)hist)[64 + lane]  = 0;
    ((int*)hist)[128 + lane] = 0;

    const int ch = lane & 31, h = lane >> 5;
    const float wp0 = w_p1[ch], wp1 = w_p1[32 + ch], wp2 = w_p1[64 + ch], bp = b_p1[ch];
    const float wc0 = w_c1[ch], wc1 = w_c1[32 + ch], bc = b_c1[ch];

    // ---- per-lane token data into registers (clamped addresses, 40 loads) ----
    float cp[2][4][3], cd[2][4][2];
    {
        const float* gp[2] = { cont_p + (size_t)b0 * (S * 3), cont_p + (size_t)b1 * (S * 3) };
        const float* gc[2] = { cont_c + (size_t)b0 * (S * 2), cont_c + (size_t)b1 * (S * 2) };
        const int Ls[2] = { L0, L1 };
        #pragma unroll
        for (int r = 0; r < 2; ++r) {
            #pragma unroll
            for (int bt = 0; bt < 4; ++bt) {
                int t = bt * 64 + lane;
                int tc = (t < Ls[r]) ? t : (Ls[r] - 1);
                cp[r][bt][0] = gp[r][3 * tc];
                cp[r][bt][1] = gp[r][3 * tc + 1];
                cp[r][bt][2] = gp[r][3 * tc + 2];
                float2 dd = *(const float2*)&gc[r][2 * tc];
                cd[r][bt][0] = dd.x; cd[r][bt][1] = dd.y;
            }
        }
    }

    // ---- categorical pass: packed binary sums + padded-hist atomics ----
    int pk[2] = { 0, 0 };
    {
        const int*  kp[2] = { cat_p + (size_t)b0 * (S * 5), cat_p + (size_t)b1 * (S * 5) };
        const int2* kc[2] = { (const int2*)(cat_c + (size_t)b0 * (S * 2)),
                              (const int2*)(cat_c + (size_t)b1 * (S * 2)) };
        const int Ls[2] = { L0, L1 };
        #pragma unroll
        for (int r = 0; r < 2; ++r) {
            #pragma unroll
            for (int bt = 0; bt < 4; ++bt) {
                int t = bt * 64 + lane;
                if (t < Ls[r]) {
                    int v0 = kp[r][5 * t], v1 = kp[r][5 * t + 1], v2 = kp[r][5 * t + 2],
                        v3 = kp[r][5 * t + 3], v4 = kp[r][5 * t + 4];
                    int2 q = kc[r][t];
                    pk[r] += v0 + (v1 << 10) + (v2 << 20);
                    atomicAdd(&hist[r][v3], 1);
                    atomicAdd(&hist[r][11 + v4], 1);
                    atomicAdd(&hist[r][46 + q.x], 1);
                    atomicAdd(&hist[r][65 + q.y], 1);
                }
            }
        }
        #pragma unroll
        for (int d = 32; d; d >>= 1) {
            pk[0] += __shfl_xor(pk[0], d);
            pk[1] += __shfl_xor(pk[1], d);
        }
    }
    const float sg0 = (float)(pk[0] & 1023), sk0 = (float)((pk[0] >> 10) & 1023),
                sp0 = (float)(pk[0] >> 20);
    const float sg1 = (float)(pk[1] & 1023), sk1 = (float)((pk[1] >> 10) & 1023),
                sp1 = (float)(pk[1] >> 20);

    // ---- token relu-MLP: readlane broadcast, pure VALU ----
    float accP0 = 0.f, accC0 = 0.f, accP1 = 0.f, accC1 = 0.f;
    {
        const int Ls[2] = { L0, L1 };
        #pragma unroll
        for (int r = 0; r < 2; ++r) {
            #pragma unroll
            for (int bt = 0; bt < 4; ++bt) {
                int base = bt * 64;
                if (base < Ls[r]) {
                    int cnt = Ls[r] - base; if (cnt > 64) cnt = 64;
                    #pragma unroll 8
                    for (int s = 0; s < cnt; ++s) {
                        float c0 = rlf(cp[r][bt][0], s);
                        float c1 = rlf(cp[r][bt][1], s);
                        float c2 = rlf(cp[r][bt][2], s);
                        float d0 = rlf(cd[r][bt][0], s);
                        float d1 = rlf(cd[r][bt][1], s);
                        float vP = fmaf(c0, wp0, fmaf(c1, wp1, fmaf(c2, wp2, bp)));
                        float vC = fmaf(d0, wc0, fmaf(d1, wc1, bc));
                        if (r == 0) { accP0 += fmaxf(vP, 0.f); accC0 += fmaxf(vC, 0.f); }
                        else        { accP1 += fmaxf(vP, 0.f); accC1 += fmaxf(vC, 0.f); }
                    }
                }
            }
        }
    }
    accP0 *= invL0; accC0 *= invL0; accP1 *= invL1; accC1 *= invL1;
    pacc[0][lane] = (lane < 32) ? accP0 : accC0;
    pacc[1][lane] = (lane < 32) ? accP1 : accC1;
    __syncthreads();   // B1: hist + pacc visible

    // ---- embedding weighted sums (half-wave split, uniform trips) ----
    float A0, A1;   // ep accumulators (rows 0,1)
    {
        float g0 = emb_g[ch],  g1 = emb_g[32 + ch];
        float k0 = emb_k[ch],  k1 = emb_k[32 + ch];
        float q0 = emb_pr[ch], q1 = emb_pr[32 + ch];
        float bin0 = fmaf(L0f - sg0, g0, sg0 * g1) + fmaf(L0f - sk0, k0, sk0 * k1)
                   + fmaf(L0f - sp0, q0, sp0 * q1);
        float bin1 = fmaf(L1f - sg1, g0, sg1 * g1) + fmaf(L1f - sk1, k0, sk1 * k1)
                   + fmaf(L1f - sp1, q0, sp1 * q1);
        A0 = h ? 0.f : bin0;
        A1 = h ? 0.f : bin1;
        #pragma unroll
        for (int i = 0; i < 23; ++i) {
            int b = 2 * i + h;                       // 0..45 (45 = pad, count 0)
            float c0 = (float)hist[0][b], c1 = (float)hist[1][b];
            int br = (b < 44) ? b : 44;              // clamp pad to valid addr
            const float* tp = (b < 11) ? (emb_j + b * 32) : (emb_r + (br - 11) * 32);
            float w = tp[ch];
            A0 = fmaf(c0, w, A0);
            A1 = fmaf(c1, w, A1);
        }
        A0 += __shfl_down(A0, 32);
        A1 += __shfl_down(A1, 32);
    }
    float E0 = 0.f, E1 = 0.f;   // ec accumulators
    {
        #pragma unroll
        for (int i = 0; i < 25; ++i) {
            int b = 46 + 2 * i + h;                  // 46..95
            float c0 = (float)hist[0][b], c1 = (float)hist[1][b];
            const float* tp = (b < 65) ? (emb_pl + (b - 46) * 32) : (emb_a + (b - 65) * 32);
            float w = tp[ch];
            E0 = fmaf(c0, w, E0);
            E1 = fmaf(c1, w, E1);
        }
        E0 += __shfl_down(E0, 32);
        E1 += __shfl_down(E1, 32);
    }

    // ---- 32x32 second layers, k split across halves ----
    float vp0, vp1, vc0, vc1;
    {
        float bb = b_p2[ch];
        vp0 = h ? 0.f : bb; vp1 = vp0;
        #pragma unroll
        for (int i = 0; i < 16; ++i) {
            int k = h * 16 + i;
            float w = w_p2[k * 32 + ch];
            vp0 = fmaf(pacc[0][k], w, vp0);          // 2 distinct LDS addrs/wave: free
            vp1 = fmaf(pacc[1][k], w, vp1);
        }
        vp0 += __shfl_down(vp0, 32);
        vp1 += __shfl_down(vp1, 32);
        float bb2 = b_c2[ch];
        vc0 = h ? 0.f : bb2; vc1 = vc0;
        #pragma unroll
        for (int i = 0; i < 16; ++i) {
            int k = h * 16 + i;
            float w = w_c2[k * 32 + ch];
            vc0 = fmaf(pacc[0][32 + k], w, vc0);
            vc1 = fmaf(pacc[1][32 + k], w, vc1);
        }
        vc0 += __shfl_down(vc0, 32);
        vc1 += __shfl_down(vc1, 32);
    }
    if (lane < 32) {
        sPool[0][ch]      = A0 * (invL0 * 0.2f);
        sPool[1][ch]      = A1 * (invL1 * 0.2f);
        sPool[0][32 + ch] = E0 * (invL0 * 0.5f);
        sPool[1][32 + ch] = E1 * (invL1 * 0.5f);
        sPool[0][64 + ch] = vp0;  sPool[1][64 + ch] = vp1;
        sPool[0][96 + ch] = vc0;  sPool[1][96 + ch] = vc1;
    }
    __syncthreads();   // B2: sPool ready

    // ---- fc1 via readlane from coalesced sPool copies; fc2 butterfly ----
    {
        float r0a = sPool[0][lane], r0b = sPool[0][64 + lane];
        float r1a = sPool[1][lane], r1b = sPool[1][64 + lane];
        float x0 = b_fc1[lane], x1 = x0, y0 = 0.f, y1 = 0.f;
        #pragma unroll
        for (int k = 0; k < 64; k += 2) {
            float wa = w_fc1[(size_t)k * 64 + lane];
            float wb = w_fc1[(size_t)(k + 1) * 64 + lane];
            x0 = fmaf(rlf(r0a, k), wa, x0);  y0 = fmaf(rlf(r0a, k + 1), wb, y0);
            x1 = fmaf(rlf(r1a, k), wa, x1);  y1 = fmaf(rlf(r1a, k + 1), wb, y1);
        }
        #pragma unroll
        for (int k = 0; k < 64; k += 2) {
            float wa = w_fc1[(size_t)(64 + k) * 64 + lane];
            float wb = w_fc1[(size_t)(65 + k) * 64 + lane];
            x0 = fmaf(rlf(r0b, k), wa, x0);  y0 = fmaf(rlf(r0b, k + 1), wb, y0);
            x1 = fmaf(rlf(r1b, k), wa, x1);  y1 = fmaf(rlf(r1b, k + 1), wb, y1);
        }
        float h0v = fmaxf(x0 + y0, 0.f);
        float h1v = fmaxf(x1 + y1, 0.f);
        float wa = w_fc2[2 * lane], wb = w_fc2[2 * lane + 1];
        float q00 = h0v * wa, q01 = h0v * wb, q10 = h1v * wa, q11 = h1v * wb;
        #pragma unroll
        for (int d = 32; d; d >>= 1) {
            q00 += __shfl_xor(q00, d); q01 += __shfl_xor(q01, d);
            q10 += __shfl_xor(q10, d); q11 += __shfl_xor(q11, d);
        }
        if (lane == 0) {
            float bb0 = b_fc2[0], bb1 = b_fc2[1];
            float4 o4;
            o4.x = fmaxf(q00 + bb0, 0.f);
            o4.y = fmaxf(q01 + bb1, 0.f);
            o4.z = fmaxf(q10 + bb0, 0.f);
            o4.w = fmaxf(q11 + bb1, 0.f);
            *(float4*)&out[(size_t)b0 * 2] = o4;
        }
    }
}

extern "C" void kernel_launch(void* const* d_in, const int* in_sizes, int n_in,
                              void* d_out, int out_size, void* d_ws, size_t ws_size,
                              hipStream_t stream) {
    const float* cont_p = (const float*)d_in[0];
    const float* cont_c = (const float*)d_in[1];
    const int*   cat_p  = (const int*)d_in[2];
    const int*   cat_c  = (const int*)d_in[3];
    const int*   lens   = (const int*)d_in[4];
    const float* w_p1   = (const float*)d_in[5];
    const float* b_p1   = (const float*)d_in[6];
    const float* w_p2   = (const float*)d_in[7];
    const float* b_p2   = (const float*)d_in[8];
    const float* w_c1   = (const float*)d_in[9];
    const float* b_c1   = (const float*)d_in[10];
    const float* w_c2   = (const float*)d_in[11];
    const float* b_c2   = (const float*)d_in[12];
    const float* emb_g  = (const float*)d_in[13];
    const float* emb_k  = (const float*)d_in[14];
    const float* emb_pr = (const float*)d_in[15];
    const float* emb_j  = (const float*)d_in[16];
    const float* emb_r  = (const float*)d_in[17];
    const float* emb_pl = (const float*)d_in[18];
    const float* emb_a  = (const float*)d_in[19];
    const float* w_fc1  = (const float*)d_in[20];
    const float* b_fc1  = (const float*)d_in[21];
    const float* w_fc2  = (const float*)d_in[22];
    const float* b_fc2  = (const float*)d_in[23];
    float* out = (float*)d_out;

    hipLaunchKernelGGL(mlpreg_kernel, dim3(2048), dim3(BDIM), 0, stream,
                       cont_p, cont_c, cat_p, cat_c, lens,
                       w_p1, b_p1, w_p2, b_p2, w_c1, b_c1, w_c2, b_c2,
                       emb_g, emb_k, emb_pr, emb_j, emb_r, emb_pl, emb_a,
                       w_fc1, b_fc1, w_fc2, b_fc2, out);
}

// Round 11
// 162.389 us; speedup vs baseline: 1.0286x; 1.0286x over previous
//
#include <hip/hip_runtime.h>

// R11 = R10 with the p2/c2 reduction FIXED. R10's bug: wave_sum64 over
// per-lane partial matmuls mixed different weight columns (ch=lane&31).
// Fix: log-transpose reduction (masks 16,8,4,2,1 then xor-32) reduces the
// per-lane A[32] arrays across lanes to pacc[ch] at lane ch — 64 shuffles
// total — then p2/c2 run as R9's verified k-split LDS-broadcast version.
// Token loop stays lane-owns-token (coalesced global, zero DS broadcast).

#define BDIM 64

__device__ __forceinline__ float wave_sum64(float v) {
    #pragma unroll
    for (int d = 32; d; d >>= 1) v += __shfl_xor(v, d);
    return v;
}

// Reduce a[32] element-wise across all 64 lanes; lane L returns total a[L&31].
__device__ __forceinline__ float transpose_reduce32(const float a[32], int lane) {
    float x16[16];
    {
        const bool s = (lane & 16) != 0;
        #pragma unroll
        for (int i = 0; i < 16; ++i) {
            float keep = s ? a[16 + i] : a[i];
            float send = s ? a[i] : a[16 + i];
            x16[i] = keep + __shfl_xor(send, 16);
        }
    }
    float x8[8];
    {
        const bool s = (lane & 8) != 0;
        #pragma unroll
        for (int i = 0; i < 8; ++i) {
            float keep = s ? x16[8 + i] : x16[i];
            float send = s ? x16[i] : x16[8 + i];
            x8[i] = keep + __shfl_xor(send, 8);
        }
    }
    float x4[4];
    {
        const bool s = (lane & 4) != 0;
        #pragma unroll
        for (int i = 0; i < 4; ++i) {
            float keep = s ? x8[4 + i] : x8[i];
            float send = s ? x8[i] : x8[4 + i];
            x4[i] = keep + __shfl_xor(send, 4);
        }
    }
    float x2[2];
    {
        const bool s = (lane & 2) != 0;
        #pragma unroll
        for (int i = 0; i < 2; ++i) {
            float keep = s ? x2[0] * 0.f + x4[2 + i] : x4[i];   // avoid self-ref; see below
            (void)keep;
            float k2 = s ? x4[2 + i] : x4[i];
            float send = s ? x4[i] : x4[2 + i];
            x2[i] = k2 + __shfl_xor(send, 2);
        }
    }
    float v;
    {
        const bool s = (lane & 1) != 0;
        float keep = s ? x2[1] : x2[0];
        float send = s ? x2[0] : x2[1];
        v = keep + __shfl_xor(send, 1);
    }
    v += __shfl_xor(v, 32);   // join the two 32-lane halves
    return v;
}

__global__ __launch_bounds__(BDIM, 4)
void mlpreg_kernel(const float* __restrict__ cont_p,
                   const float* __restrict__ cont_c,
                   const int* __restrict__ cat_p,
                   const int* __restrict__ cat_c,
                   const int* __restrict__ lengths,
                   const float* __restrict__ w_p1, const float* __restrict__ b_p1,
                   const float* __restrict__ w_p2, const float* __restrict__ b_p2,
                   const float* __restrict__ w_c1, const float* __restrict__ b_c1,
                   const float* __restrict__ w_c2, const float* __restrict__ b_c2,
                   const float* __restrict__ emb_g,  const float* __restrict__ emb_k,
                   const float* __restrict__ emb_pr, const float* __restrict__ emb_j,
                   const float* __restrict__ emb_r,  const float* __restrict__ emb_pl,
                   const float* __restrict__ emb_a,
                   const float* __restrict__ w_fc1, const float* __restrict__ b_fc1,
                   const float* __restrict__ w_fc2, const float* __restrict__ b_fc2,
                   float* __restrict__ out)
{
    constexpr int S = 256;
    __shared__ int   hist[96];    // job@0(11) rep@11(34) pad@45 place@46(19) add@65(31)
    __shared__ float sPacc[64];
    __shared__ __align__(16) float sPool[128];  // [ep | ec | hp2 | hc2]

    const int lane = threadIdx.x;
    const int b    = blockIdx.x;
    int L = lengths[b];
    L = (L < 1) ? 1 : (L > S ? S : L);
    const float Lf = (float)L, invL = 1.0f / Lf;

    hist[lane] = 0;
    if (lane < 32) hist[64 + lane] = 0;

    const int ch = lane & 31, h = lane >> 5;
    const float* gp = cont_p + (size_t)b * (S * 3);
    const float* gc = cont_c + (size_t)b * (S * 2);
    const int*   kp = cat_p  + (size_t)b * (S * 5);
    const int*   kc = cat_c  + (size_t)b * (S * 2);

    // ---- pre-issue token blocks 0,1 cont data (clamped addr, masked) ----
    const int t0 = lane, t1 = 64 + lane;
    const int i0 = (t0 < L) ? t0 : (L - 1);
    const int i1 = (t1 < L) ? t1 : (L - 1);
    const float m0 = (t0 < L) ? 1.f : 0.f;
    const float m1 = (t1 < L) ? 1.f : 0.f;
    float a00 = gp[3 * i0], a01 = gp[3 * i0 + 1], a02 = gp[3 * i0 + 2];
    float2 e0 = *(const float2*)&gc[2 * i0];
    float a10 = gp[3 * i1], a11 = gp[3 * i1 + 1], a12 = gp[3 * i1 + 2];
    float2 e1 = *(const float2*)&gc[2 * i1];

    // ---- categorical pass (LDS atomics + packed binary sums) ----
    int pk = 0;
    #pragma unroll
    for (int blk = 0; blk < 4; ++blk) {
        if (L > blk * 64) {
            int t = blk * 64 + lane;
            if (t < L) {
                int v0 = kp[5 * t], v1 = kp[5 * t + 1], v2 = kp[5 * t + 2],
                    v3 = kp[5 * t + 3], v4 = kp[5 * t + 4];
                int2 q = *(const int2*)&kc[2 * t];
                pk += v0 + (v1 << 10) + (v2 << 20);
                atomicAdd(&hist[v3], 1);
                atomicAdd(&hist[11 + v4], 1);
                atomicAdd(&hist[46 + q.x], 1);
                atomicAdd(&hist[65 + q.y], 1);
            }
        }
    }
    #pragma unroll
    for (int d = 32; d; d >>= 1) pk += __shfl_xor(pk, d);
    const float sg = (float)(pk & 1023), sk = (float)((pk >> 10) & 1023),
                sp = (float)(pk >> 20);

    // ---- channel sweep: AP[j]/AC[j] = sum over my tokens of relu(...) ----
    float AP[32], AC[32];
    #pragma unroll
    for (int j = 0; j < 32; ++j) {
        float vp = fmaf(a00, w_p1[j], fmaf(a01, w_p1[32 + j], fmaf(a02, w_p1[64 + j], b_p1[j])));
        AP[j] = m0 * fmaxf(vp, 0.f);
        float vc = fmaf(e0.x, w_c1[j], fmaf(e0.y, w_c1[32 + j], b_c1[j]));
        AC[j] = m0 * fmaxf(vc, 0.f);
    }
    if (L > 64) {
        #pragma unroll
        for (int j = 0; j < 32; ++j) {
            float vp = fmaf(a10, w_p1[j], fmaf(a11, w_p1[32 + j], fmaf(a12, w_p1[64 + j], b_p1[j])));
            AP[j] = fmaf(m1, fmaxf(vp, 0.f), AP[j]);
            float vc = fmaf(e1.x, w_c1[j], fmaf(e1.y, w_c1[32 + j], b_c1[j]));
            AC[j] = fmaf(m1, fmaxf(vc, 0.f), AC[j]);
        }
    }
    if (L > 128) {
        int t = 128 + lane;
        int ti = (t < L) ? t : (L - 1);
        float m = (t < L) ? 1.f : 0.f;
        float c0 = gp[3 * ti], c1 = gp[3 * ti + 1], c2 = gp[3 * ti + 2];
        float2 dd = *(const float2*)&gc[2 * ti];
        #pragma unroll
        for (int j = 0; j < 32; ++j) {
            float vp = fmaf(c0, w_p1[j], fmaf(c1, w_p1[32 + j], fmaf(c2, w_p1[64 + j], b_p1[j])));
            AP[j] = fmaf(m, fmaxf(vp, 0.f), AP[j]);
            float vc = fmaf(dd.x, w_c1[j], fmaf(dd.y, w_c1[32 + j], b_c1[j]));
            AC[j] = fmaf(m, fmaxf(vc, 0.f), AC[j]);
        }
    }
    if (L > 192) {
        int t = 192 + lane;
        int ti = (t < L) ? t : (L - 1);
        float m = (t < L) ? 1.f : 0.f;
        float c0 = gp[3 * ti], c1 = gp[3 * ti + 1], c2 = gp[3 * ti + 2];
        float2 dd = *(const float2*)&gc[2 * ti];
        #pragma unroll
        for (int j = 0; j < 32; ++j) {
            float vp = fmaf(c0, w_p1[j], fmaf(c1, w_p1[32 + j], fmaf(c2, w_p1[64 + j], b_p1[j])));
            AP[j] = fmaf(m, fmaxf(vp, 0.f), AP[j]);
            float vc = fmaf(dd.x, w_c1[j], fmaf(dd.y, w_c1[32 + j], b_c1[j]));
            AC[j] = fmaf(m, fmaxf(vc, 0.f), AC[j]);
        }
    }

    // ---- CORRECT pacc: transpose-reduce across lanes, stash in LDS ----
    float paccP = transpose_reduce32(AP, lane);   // lane holds pacc_P[lane&31]
    float paccC = transpose_reduce32(AC, lane);
    if (lane < 32) {
        sPacc[ch]      = paccP * invL;
        sPacc[32 + ch] = paccC * invL;
    }
    __syncthreads();   // orders hist atomics + sPacc writes before reads

    // ---- p2/c2 (R9-verified k-split halves, LDS broadcast reads) ----
    float vp0 = h ? 0.f : b_p2[ch];
    #pragma unroll
    for (int i = 0; i < 16; ++i) {
        int k = h * 16 + i;
        vp0 = fmaf(sPacc[k], w_p2[k * 32 + ch], vp0);
    }
    vp0 += __shfl_down(vp0, 32);
    float vc0 = h ? 0.f : b_c2[ch];
    #pragma unroll
    for (int i = 0; i < 16; ++i) {
        int k = h * 16 + i;
        vc0 = fmaf(sPacc[32 + k], w_c2[k * 32 + ch], vc0);
    }
    vc0 += __shfl_down(vc0, 32);

    // ---- embedding weighted sums (half-wave split over padded hist bins) ----
    float ep = 0.f;
    if (h == 0) {
        ep  = fmaf(Lf - sg, emb_g[ch],  sg * emb_g[32 + ch]);
        ep += fmaf(Lf - sk, emb_k[ch],  sk * emb_k[32 + ch]);
        ep += fmaf(Lf - sp, emb_pr[ch], sp * emb_pr[32 + ch]);
    }
    #pragma unroll
    for (int i = 0; i < 23; ++i) {
        int bb = 2 * i + h;                       // 0..45 (45 = pad, count 0)
        int cnt = hist[bb];
        int br = (bb < 44) ? bb : 44;
        const float* tp = (bb < 11) ? (emb_j + bb * 32) : (emb_r + (br - 11) * 32);
        ep = fmaf((float)cnt, tp[ch], ep);
    }
    ep += __shfl_down(ep, 32);
    float ec = 0.f;
    #pragma unroll
    for (int i = 0; i < 25; ++i) {
        int bb = 46 + 2 * i + h;                  // 46..95
        int cnt = hist[bb];
        const float* tp = (bb < 65) ? (emb_pl + (bb - 46) * 32) : (emb_a + (bb - 65) * 32);
        ec = fmaf((float)cnt, tp[ch], ec);
    }
    ec += __shfl_down(ec, 32);

    if (lane < 32) {
        sPool[ch]      = ep * (invL * 0.2f);
        sPool[32 + ch] = ec * (invL * 0.5f);
        sPool[64 + ch] = vp0;
        sPool[96 + ch] = vc0;
    }
    __syncthreads();   // sPool visible to whole wave

    // ---- fc1: 128 -> 64 (b128 LDS broadcast + coalesced weights) ----
    float q0 = b_fc1[lane], q1 = 0.f, q2 = 0.f, q3 = 0.f;
    #pragma unroll
    for (int k4 = 0; k4 < 32; ++k4) {
        float4 x = *(const float4*)&sPool[4 * k4];
        q0 = fmaf(x.x, w_fc1[(size_t)(4 * k4 + 0) * 64 + lane], q0);
        q1 = fmaf(x.y, w_fc1[(size_t)(4 * k4 + 1) * 64 + lane], q1);
        q2 = fmaf(x.z, w_fc1[(size_t)(4 * k4 + 2) * 64 + lane], q2);
        q3 = fmaf(x.w, w_fc1[(size_t)(4 * k4 + 3) * 64 + lane], q3);
    }
    float hv = fmaxf((q0 + q1) + (q2 + q3), 0.f);

    // ---- fc2: 64 -> 2 butterfly + store ----
    float2 wf = *(const float2*)&w_fc2[2 * lane];
    float p0 = wave_sum64(hv * wf.x);
    float p1 = wave_sum64(hv * wf.y);
    if (lane == 0) {
        float2 o2;
        o2.x = fmaxf(p0 + b_fc2[0], 0.f);
        o2.y = fmaxf(p1 + b_fc2[1], 0.f);
        *(float2*)&out[(size_t)b * 2] = o2;
    }
}

extern "C" void kernel_launch(void* const* d_in, const int* in_sizes, int n_in,
                              void* d_out, int out_size, void* d_ws, size_t ws_size,
                              hipStream_t stream) {
    const float* cont_p = (const float*)d_in[0];
    const float* cont_c = (const float*)d_in[1];
    const int*   cat_p  = (const int*)d_in[2];
    const int*   cat_c  = (const int*)d_in[3];
    const int*   lens   = (const int*)d_in[4];
    const float* w_p1   = (const float*)d_in[5];
    const float* b_p1   = (const float*)d_in[6];
    const float* w_p2   = (const float*)d_in[7];
    const float* b_p2   = (const float*)d_in[8];
    const float* w_c1   = (const float*)d_in[9];
    const float* b_c1   = (const float*)d_in[10];
    const float* w_c2   = (const float*)d_in[11];
    const float* b_c2   = (const float*)d_in[12];
    const float* emb_g  = (const float*)d_in[13];
    const float* emb_k  = (const float*)d_in[14];
    const float* emb_pr = (const float*)d_in[15];
    const float* emb_j  = (const float*)d_in[16];
    const float* emb_r  = (const float*)d_in[17];
    const float* emb_pl = (const float*)d_in[18];
    const float* emb_a  = (const float*)d_in[19];
    const float* w_fc1  = (const float*)d_in[20];
    const float* b_fc1  = (const float*)d_in[21];
    const float* w_fc2  = (const float*)d_in[22];
    const float* b_fc2  = (const float*)d_in[23];
    float* out = (float*)d_out;

    hipLaunchKernelGGL(mlpreg_kernel, dim3(4096), dim3(BDIM), 0, stream,
                       cont_p, cont_c, cat_p, cat_c, lens,
                       w_p1, b_p1, w_p2, b_p2, w_c1, b_c1, w_c2, b_c2,
                       emb_g, emb_k, emb_pr, emb_j, emb_r, emb_pl, emb_a,
                       w_fc1, b_fc1, w_fc2, b_fc2, out);
}

// Round 12
// 146.475 us; speedup vs baseline: 1.1404x; 1.1086x over previous
//
#include <hip/hip_runtime.h>

// R12: channel-per-lane token loop. R11 post-mortem showed the 64-element
// per-lane accumulator array was silently allocated to AGPRs (VGPR_Count=56)
// making every accumulate 3 VALU insts + per-block weight reloads. Here each
// lane owns ONE channel (lanes 0-31: P-ch, 32-63: C-ch), so pacc is 1
// register per lane, weights are 4 per-lane registers loaded once, and the
// token loop reads ONE ds_read_b128 per token from 8-float LDS records
// [p0 p1 p2 _ c0 c1 _ _] (2 addrs/wave = free 2-way aliasing).
// Tail (hist, embedding weighted sums, p2/c2, fc1, fc2) identical to R11's
// verified code paths. 1 row per 64-lane wave, grid 4096 -> 16 waves/CU.

#define BDIM 64

__device__ __forceinline__ float wave_sum64(float v) {
    #pragma unroll
    for (int d = 32; d; d >>= 1) v += __shfl_xor(v, d);
    return v;
}

__global__ __launch_bounds__(BDIM, 4)
void mlpreg_kernel(const float* __restrict__ cont_p,
                   const float* __restrict__ cont_c,
                   const int* __restrict__ cat_p,
                   const int* __restrict__ cat_c,
                   const int* __restrict__ lengths,
                   const float* __restrict__ w_p1, const float* __restrict__ b_p1,
                   const float* __restrict__ w_p2, const float* __restrict__ b_p2,
                   const float* __restrict__ w_c1, const float* __restrict__ b_c1,
                   const float* __restrict__ w_c2, const float* __restrict__ b_c2,
                   const float* __restrict__ emb_g,  const float* __restrict__ emb_k,
                   const float* __restrict__ emb_pr, const float* __restrict__ emb_j,
                   const float* __restrict__ emb_r,  const float* __restrict__ emb_pl,
                   const float* __restrict__ emb_a,
                   const float* __restrict__ w_fc1, const float* __restrict__ b_fc1,
                   const float* __restrict__ w_fc2, const float* __restrict__ b_fc2,
                   float* __restrict__ out)
{
    constexpr int S = 256;
    __shared__ __align__(16) float sTok[S * 8];   // 8 KB: [p0 p1 p2 _ c0 c1 _ _]
    __shared__ int   hist[96];    // job@0(11) rep@11(34) pad@45 place@46(19) add@65(31)
    __shared__ float sPacc[64];
    __shared__ __align__(16) float sPool[128];    // [ep | ec | hp2 | hc2]

    const int lane = threadIdx.x;
    const int b    = blockIdx.x;
    int L = lengths[b];
    L = (L < 1) ? 1 : (L > S ? S : L);
    const float Lf = (float)L, invL = 1.0f / Lf;

    hist[lane] = 0;
    if (lane < 32) hist[64 + lane] = 0;

    const int ch = lane & 31, h = lane >> 5;
    const float* gp = cont_p + (size_t)b * (S * 3);
    const float* gc = cont_c + (size_t)b * (S * 2);
    const int*   kp = cat_p  + (size_t)b * (S * 5);
    const int*   kc = cat_c  + (size_t)b * (S * 2);

    // ---- per-lane first-layer weights (4 regs; c-lanes use w2 = 0) ----
    const float w0 = h ? w_c1[ch]      : w_p1[ch];
    const float w1 = h ? w_c1[32 + ch] : w_p1[32 + ch];
    const float w2 = h ? 0.f           : w_p1[64 + ch];
    const float bb = h ? b_c1[ch]      : b_p1[ch];

    // ---- stage tokens into 8-float records (coalesced global reads) ----
    for (int i = lane; i < 3 * L; i += BDIM) {
        int t = i / 3, r = i - 3 * t;
        sTok[t * 8 + r] = gp[i];
    }
    for (int i = lane; i < 2 * L; i += BDIM) {
        int t = i >> 1, r = i & 1;
        sTok[t * 8 + 4 + r] = gc[i];
    }

    // ---- categorical pass (verified R11 path) ----
    int pk = 0;
    #pragma unroll
    for (int blk = 0; blk < 4; ++blk) {
        if (L > blk * 64) {
            int t = blk * 64 + lane;
            if (t < L) {
                int v0 = kp[5 * t], v1 = kp[5 * t + 1], v2 = kp[5 * t + 2],
                    v3 = kp[5 * t + 3], v4 = kp[5 * t + 4];
                int2 q = *(const int2*)&kc[2 * t];
                pk += v0 + (v1 << 10) + (v2 << 20);
                atomicAdd(&hist[v3], 1);
                atomicAdd(&hist[11 + v4], 1);
                atomicAdd(&hist[46 + q.x], 1);
                atomicAdd(&hist[65 + q.y], 1);
            }
        }
    }
    #pragma unroll
    for (int d = 32; d; d >>= 1) pk += __shfl_xor(pk, d);
    const float sg = (float)(pk & 1023), sk = (float)((pk >> 10) & 1023),
                sp = (float)(pk >> 20);

    __syncthreads();   // sTok records + hist visible wave-wide

    // ---- token loop: 1 ds_read_b128 per token, 1 acc reg per lane ----
    const int off = h << 2;   // 0 for p-lanes, 4 for c-lanes
    float acc0 = 0.f, acc1 = 0.f;
    int t = 0;
    for (; t + 1 < L; t += 2) {
        float4 va = *(const float4*)&sTok[t * 8 + off];
        float4 vb = *(const float4*)&sTok[(t + 1) * 8 + off];
        acc0 += fmaxf(fmaf(va.x, w0, fmaf(va.y, w1, fmaf(va.z, w2, bb))), 0.f);
        acc1 += fmaxf(fmaf(vb.x, w0, fmaf(vb.y, w1, fmaf(vb.z, w2, bb))), 0.f);
    }
    if (t < L) {
        float4 va = *(const float4*)&sTok[t * 8 + off];
        acc0 += fmaxf(fmaf(va.x, w0, fmaf(va.y, w1, fmaf(va.z, w2, bb))), 0.f);
    }
    sPacc[lane] = (acc0 + acc1) * invL;   // lane<32: pacc_p[ch], else pacc_c[ch]
    __syncthreads();

    // ---- p2/c2 (R9/R11-verified k-split halves, LDS broadcast reads) ----
    float vp0 = h ? 0.f : b_p2[ch];
    #pragma unroll
    for (int i = 0; i < 16; ++i) {
        int k = h * 16 + i;
        vp0 = fmaf(sPacc[k], w_p2[k * 32 + ch], vp0);
    }
    vp0 += __shfl_down(vp0, 32);
    float vc0 = h ? 0.f : b_c2[ch];
    #pragma unroll
    for (int i = 0; i < 16; ++i) {
        int k = h * 16 + i;
        vc0 = fmaf(sPacc[32 + k], w_c2[k * 32 + ch], vc0);
    }
    vc0 += __shfl_down(vc0, 32);

    // ---- embedding weighted sums (R11-verified padded-bin half split) ----
    float ep = 0.f;
    if (h == 0) {
        ep  = fmaf(Lf - sg, emb_g[ch],  sg * emb_g[32 + ch]);
        ep += fmaf(Lf - sk, emb_k[ch],  sk * emb_k[32 + ch]);
        ep += fmaf(Lf - sp, emb_pr[ch], sp * emb_pr[32 + ch]);
    }
    #pragma unroll
    for (int i = 0; i < 23; ++i) {
        int bb2 = 2 * i + h;                      // 0..45 (45 = pad, count 0)
        int cnt = hist[bb2];
        int br = (bb2 < 44) ? bb2 : 44;
        const float* tp = (bb2 < 11) ? (emb_j + bb2 * 32) : (emb_r + (br - 11) * 32);
        ep = fmaf((float)cnt, tp[ch], ep);
    }
    ep += __shfl_down(ep, 32);
    float ec = 0.f;
    #pragma unroll
    for (int i = 0; i < 25; ++i) {
        int bb2 = 46 + 2 * i + h;                 // 46..95
        int cnt = hist[bb2];
        const float* tp = (bb2 < 65) ? (emb_pl + (bb2 - 46) * 32) : (emb_a + (bb2 - 65) * 32);
        ec = fmaf((float)cnt, tp[ch], ec);
    }
    ec += __shfl_down(ec, 32);

    if (lane < 32) {
        sPool[ch]      = ep * (invL * 0.2f);
        sPool[32 + ch] = ec * (invL * 0.5f);
        sPool[64 + ch] = vp0;
        sPool[96 + ch] = vc0;
    }
    __syncthreads();   // sPool visible

    // ---- fc1: 128 -> 64 (b128 LDS broadcast + coalesced weights) ----
    float q0 = b_fc1[lane], q1 = 0.f, q2 = 0.f, q3 = 0.f;
    #pragma unroll
    for (int k4 = 0; k4 < 32; ++k4) {
        float4 x = *(const float4*)&sPool[4 * k4];
        q0 = fmaf(x.x, w_fc1[(size_t)(4 * k4 + 0) * 64 + lane], q0);
        q1 = fmaf(x.y, w_fc1[(size_t)(4 * k4 + 1) * 64 + lane], q1);
        q2 = fmaf(x.z, w_fc1[(size_t)(4 * k4 + 2) * 64 + lane], q2);
        q3 = fmaf(x.w, w_fc1[(size_t)(4 * k4 + 3) * 64 + lane], q3);
    }
    float hv = fmaxf((q0 + q1) + (q2 + q3), 0.f);

    // ---- fc2: 64 -> 2 butterfly + store ----
    float2 wf = *(const float2*)&w_fc2[2 * lane];
    float p0 = wave_sum64(hv * wf.x);
    float p1 = wave_sum64(hv * wf.y);
    if (lane == 0) {
        float2 o2;
        o2.x = fmaxf(p0 + b_fc2[0], 0.f);
        o2.y = fmaxf(p1 + b_fc2[1], 0.f);
        *(float2*)&out[(size_t)b * 2] = o2;
    }
}

extern "C" void kernel_launch(void* const* d_in, const int* in_sizes, int n_in,
                              void* d_out, int out_size, void* d_ws, size_t ws_size,
                              hipStream_t stream) {
    const float* cont_p = (const float*)d_in[0];
    const float* cont_c = (const float*)d_in[1];
    const int*   cat_p  = (const int*)d_in[2];
    const int*   cat_c  = (const int*)d_in[3];
    const int*   lens   = (const int*)d_in[4];
    const float* w_p1   = (const float*)d_in[5];
    const float* b_p1   = (const float*)d_in[6];
    const float* w_p2   = (const float*)d_in[7];
    const float* b_p2   = (const float*)d_in[8];
    const float* w_c1   = (const float*)d_in[9];
    const float* b_c1   = (const float*)d_in[10];
    const float* w_c2   = (const float*)d_in[11];
    const float* b_c2   = (const float*)d_in[12];
    const float* emb_g  = (const float*)d_in[13];
    const float* emb_k  = (const float*)d_in[14];
    const float* emb_pr = (const float*)d_in[15];
    const float* emb_j  = (const float*)d_in[16];
    const float* emb_r  = (const float*)d_in[17];
    const float* emb_pl = (const float*)d_in[18];
    const float* emb_a  = (const float*)d_in[19];
    const float* w_fc1  = (const float*)d_in[20];
    const float* b_fc1  = (const float*)d_in[21];
    const float* w_fc2  = (const float*)d_in[22];
    const float* b_fc2  = (const float*)d_in[23];
    float* out = (float*)d_out;

    hipLaunchKernelGGL(mlpreg_kernel, dim3(4096), dim3(BDIM), 0, stream,
                       cont_p, cont_c, cat_p, cat_c, lens,
                       w_p1, b_p1, w_p2, b_p2, w_c1, b_c1, w_c2, b_c2,
                       emb_g, emb_k, emb_pr, emb_j, emb_r, emb_pl, emb_a,
                       w_fc1, b_fc1, w_fc2, b_fc2, out);
}